// Round 13
// baseline (131.016 us; speedup 1.0000x reference)
//
#include <hip/hip_runtime.h>
#include <hip/hip_bf16.h>
#include <stdint.h>

#define IN_F  4096
#define OUT_F 11008
#define MTOT  512

#define BM 128
#define BN 64
#define BK 64
#define NKT (IN_F / BK)            // 64 K-tiles
#define NTILES (OUT_F / BN)        // 172

// i8 fragment blocks
#define XT_B 8192                  // A: per (mtile,kt): 8 frags x 1 KB
#define WT_B 4096                  // B: per (ntile,kt): 4 frags x 1 KB

// ws layout (full tier): [0,2MB) X-i8 frags | [2MB,+2KB) sx | [4MB,..) W-i8 frags
#define SX_OFF   ((size_t)MTOT * IN_F)                    // 2 MiB
#define WWS_OFF  ((size_t)4 * 1024 * 1024)
#define W_I8_BYTES ((size_t)NTILES * NKT * WT_B)          // 45,088,768
#define WS_FULL  (WWS_OFF + W_I8_BYTES)                   // ~47 MiB
#define WS_MID   ((size_t)MTOT * IN_F * 2)                // 4 MiB (R8 bf16 tier)

typedef __attribute__((ext_vector_type(4))) float  f32x4;
typedef __attribute__((ext_vector_type(4))) int    i32x4;
typedef __attribute__((ext_vector_type(2))) unsigned u32x2;
typedef __attribute__((ext_vector_type(4))) unsigned u32x4;
typedef __attribute__((ext_vector_type(8))) __bf16 bf16x8;

__device__ __forceinline__ unsigned pack2bf16_rnd(float lo, float hi) {
    unsigned ulo = __builtin_bit_cast(unsigned, lo) + 0x8000u;
    unsigned uhi = __builtin_bit_cast(unsigned, hi) + 0x8000u;
    return __builtin_amdgcn_perm(uhi, ulo, 0x07060302u);
}
__device__ __forceinline__ unsigned pack2bf16_exact(float lo, float hi) {
    return __builtin_amdgcn_perm(__builtin_bit_cast(unsigned, hi),
                                 __builtin_bit_cast(unsigned, lo), 0x07060302u);
}
// 4 int32 (in [-128,127]) -> 4 packed i8 bytes
__device__ __forceinline__ unsigned pack4_i8(i32x4 v) {
    unsigned r1 = __builtin_amdgcn_perm((unsigned)v.y, (unsigned)v.x, 0x00000400u);
    unsigned r2 = __builtin_amdgcn_perm((unsigned)v.w, (unsigned)v.z, 0x00000400u);
    return __builtin_amdgcn_perm(r2, r1, 0x05040100u);
}

#define BAR() do {                                                 \
    asm volatile("s_waitcnt lgkmcnt(0)" ::: "memory");             \
    __builtin_amdgcn_s_barrier();                                  \
    __builtin_amdgcn_sched_barrier(0);                             \
} while (0)

// ============================ FULL TIER (i8 frag-frag) ======================

// X fp32 -> per-row i8, MFMA-fragment order (R12-verified layout).
__global__ __launch_bounds__(256)
void xconv_i8_kernel(const float* __restrict__ X, char* __restrict__ xws,
                     float* __restrict__ sx) {
    const int row = (int)blockIdx.x;     // 512 rows
    const int t   = (int)threadIdx.x;    // 16 cols each
    const float* src = X + (size_t)row * IN_F + t * 16;
    f32x4 v0 = *(const f32x4*)(src);
    f32x4 v1 = *(const f32x4*)(src + 4);
    f32x4 v2 = *(const f32x4*)(src + 8);
    f32x4 v3 = *(const f32x4*)(src + 12);

    float m = 0.f;
    #pragma unroll
    for (int i = 0; i < 4; ++i)
        m = fmaxf(m, fmaxf(fmaxf(fabsf(v0[i]), fabsf(v1[i])),
                           fmaxf(fabsf(v2[i]), fabsf(v3[i]))));
    #pragma unroll
    for (int off = 32; off >= 1; off >>= 1)
        m = fmaxf(m, __shfl_xor(m, off));
    __shared__ float red[4];
    if ((t & 63) == 0) red[t >> 6] = m;
    __syncthreads();
    m = fmaxf(fmaxf(red[0], red[1]), fmaxf(red[2], red[3]));
    m = fmaxf(m, 1e-20f);
    const float inv = 127.0f / m;
    if (t == 0) sx[row] = m * (1.0f / 127.0f);

    i32x4 q0, q1, q2, q3;
    #pragma unroll
    for (int i = 0; i < 4; ++i) {
        q0[i] = (int)__builtin_rintf(v0[i] * inv);
        q1[i] = (int)__builtin_rintf(v1[i] * inv);
        q2[i] = (int)__builtin_rintf(v2[i] * inv);
        q3[i] = (int)__builtin_rintf(v3[i] * inv);
    }
    u32x4 o;
    o.x = pack4_i8(q0); o.y = pack4_i8(q1);
    o.z = pack4_i8(q2); o.w = pack4_i8(q3);

    const int mtile = row >> 7, mrow = row & 127;
    const int f = mrow >> 4, l15 = mrow & 15;
    const int kt = t >> 2;
    const int h  = t & 3;
    const int lane = h * 16 + l15;
    *(u32x4*)(xws + ((size_t)(mtile * NKT + kt)) * XT_B + f * 1024
                  + lane * 16) = o;
}

// W int32 -> i8, MFMA-B-fragment order: frag block per (ntile,kt), 4 frags.
// Slot (f, lane l) = W[ntile*64 + f*16 + (l&15)][kt*64 + (l>>4)*16 .. +16].
__global__ __launch_bounds__(256)
void wconv_kernel(const int* __restrict__ W, char* __restrict__ wws) {
    const int row = (int)blockIdx.x;     // 11008 rows
    const int t   = (int)threadIdx.x;    // 16 cols each
    const int* src = W + (size_t)row * IN_F + t * 16;
    i32x4 a = *(const i32x4*)(src);
    i32x4 b = *(const i32x4*)(src + 4);
    i32x4 c = *(const i32x4*)(src + 8);
    i32x4 d = *(const i32x4*)(src + 12);
    u32x4 o;
    o.x = pack4_i8(a); o.y = pack4_i8(b);
    o.z = pack4_i8(c); o.w = pack4_i8(d);

    const int ntile = row >> 6, nrow = row & 63;
    const int f = nrow >> 4, l15 = nrow & 15;
    const int kt = t >> 2;
    const int h  = t & 3;
    const int lane = h * 16 + l15;
    *(u32x4*)(wws + ((size_t)(ntile * NKT + kt)) * WT_B + f * 1024
                  + lane * 16) = o;
}

// GEMM: BM=128 x BN=64, 2 waves, 64x64 wave tile, i8 MFMA K=64.
// BOTH operands fragment-direct global->reg. No LDS. No barriers. No converts.
// 2-deep named register pipeline; compiler schedules waits.
__global__ __launch_bounds__(128, 2)
void qgemm_ff_kernel(const char* __restrict__ xi8, const float* __restrict__ sx,
                     const char* __restrict__ wi8,
                     const float* __restrict__ scale,
                     const float* __restrict__ bias,
                     float* __restrict__ Out)
{
    const int tid  = (int)threadIdx.x;
    const int lane = tid & 63;
    const int w    = tid >> 6;

    // XCD mapping (R8-proven): 688 = 8*86; 4 mtiles of one ntile consecutive
    // within an XCD -> X-i8 (2 MB) L2-resident, W-i8 frag lines L2-shared 8x.
    const int bid  = (int)blockIdx.x;
    const int lbid = (bid & 7) * 86 + (bid >> 3);
    const int mtile = lbid & 3;
    const int ntile = lbid >> 2;
    const int brow = mtile * BM;
    const int bcol = ntile * BN;

    const char* xA = xi8 + (size_t)mtile * (NKT * XT_B) + (w * 4) * 1024
                   + lane * 16;
    const char* wB = wi8 + (size_t)ntile * (NKT * WT_B) + lane * 16;

    i32x4 afE[4], afO[4], bfE[4], bfO[4];
    i32x4 acc[4][4];
    #pragma unroll
    for (int i = 0; i < 4; ++i)
        #pragma unroll
        for (int jj = 0; jj < 4; ++jj)
            acc[i][jj] = (i32x4){0, 0, 0, 0};

    #define LOAD_AF(AF, KT)                                                  \
        _Pragma("unroll")                                                    \
        for (int mi = 0; mi < 4; ++mi)                                       \
            AF[mi] = *(const i32x4*)(xA + (size_t)(KT) * XT_B + mi * 1024);

    #define LOAD_BF(BF, KT)                                                  \
        _Pragma("unroll")                                                    \
        for (int ni = 0; ni < 4; ++ni)                                       \
            BF[ni] = *(const i32x4*)(wB + (size_t)(KT) * WT_B + ni * 1024);

    #define MFMA_FF(AF, BF)                                                  \
        _Pragma("unroll")                                                    \
        for (int mi = 0; mi < 4; ++mi)                                       \
            _Pragma("unroll")                                                \
            for (int ni = 0; ni < 4; ++ni)                                   \
                acc[mi][ni] = __builtin_amdgcn_mfma_i32_16x16x64_i8(         \
                    AF[mi], BF[ni], acc[mi][ni], 0, 0, 0);

    // prologue
    LOAD_AF(afE, 0);
    LOAD_BF(bfE, 0);

    for (int kt2 = 0; kt2 < NKT; kt2 += 2) {
        const bool more = (kt2 + 2 < NKT);
        // issue next-tile loads, then compute current (loads fly under MFMA)
        LOAD_AF(afO, kt2 + 1);
        LOAD_BF(bfO, kt2 + 1);
        MFMA_FF(afE, bfE);
        if (more) {
            LOAD_AF(afE, kt2 + 2);
            LOAD_BF(bfE, kt2 + 2);
        }
        MFMA_FF(afO, bfO);
    }

    // epilogue: out = acc * sx[row]/scale[col] + bias[col]
    // C/D mapping: col = lane&15, row = (lane>>4)*4 + j
    #pragma unroll
    for (int ni = 0; ni < 4; ++ni) {
        const int col = bcol + ni * 16 + (lane & 15);
        const float inv = 1.0f / scale[col];
        const float bs  = bias[col];
        #pragma unroll
        for (int mi = 0; mi < 4; ++mi) {
            const int row0 = brow + w * 64 + mi * 16 + ((lane >> 4) << 2);
            const f32x4 sxq = *(const f32x4*)(sx + row0);
            #pragma unroll
            for (int jj = 0; jj < 4; ++jj)
                Out[(size_t)(row0 + jj) * OUT_F + col] =
                    (float)acc[mi][ni][jj] * (sxq[jj] * inv) + bs;
        }
    }
    #undef LOAD_AF
    #undef LOAD_BF
    #undef MFMA_FF
}

// ============================ MID TIER (R8 verbatim, bf16) ==================

#define XT16_B 16384
#define BT16_B (BN * BK * 2)

__global__ __launch_bounds__(256)
void xconv_bf16_kernel(const float* __restrict__ X, char* __restrict__ xws) {
    const int gid  = blockIdx.x * 256 + threadIdx.x;
    const int row  = gid >> 9;
    const int col0 = (gid & 511) * 8;
    const float* src = X + (size_t)row * IN_F + col0;
    f32x4 v0 = *(const f32x4*)(src);
    f32x4 v1 = *(const f32x4*)(src + 4);
    u32x4 o;
    o.x = pack2bf16_rnd(v0.x, v0.y);
    o.y = pack2bf16_rnd(v0.z, v0.w);
    o.z = pack2bf16_rnd(v1.x, v1.y);
    o.w = pack2bf16_rnd(v1.z, v1.w);
    const int mtile = row >> 7, mrow = row & 127;
    const int mi = mrow >> 4,  l15 = mrow & 15;
    const int kt  = col0 >> 6;
    const int ks  = (col0 >> 5) & 1;
    const int lhi = (col0 >> 3) & 3;
    const int lane = lhi * 16 + l15;
    const int f = mi * 2 + ks;
    *(u32x4*)(xws + ((size_t)(mtile * NKT + kt) * 16 + f) * 1024
                  + lane * 16) = o;
}

__global__ __launch_bounds__(128, 2)
void qgemm_bf16_kernel(const char* __restrict__ xws,
                       const int*   __restrict__ W,
                       const float* __restrict__ scale,
                       const float* __restrict__ bias,
                       float* __restrict__ Out)
{
    __shared__ __align__(16) char smem[2 * BT16_B];
    char* bufB0 = smem;
    char* bufB1 = smem + BT16_B;

    const int tid  = (int)threadIdx.x;
    const int lane = tid & 63;
    const int w    = tid >> 6;

    const int bid  = (int)blockIdx.x;
    const int lbid = (bid & 7) * 86 + (bid >> 3);
    const int mtile = lbid & 3;
    const int ntile = lbid >> 2;
    const int brow = mtile * BM;
    const int bcol = ntile * BN;

    const int srow  = tid >> 4;
    const int scol4 = tid & 15;
    const int* Wp = W + (size_t)(bcol + srow) * IN_F + scol4 * 4;

    const char* xAw = xws + (size_t)mtile * (NKT * XT16_B) + w * 8192 + lane * 16;

    i32x4 rb[8];
    bf16x8 afE[8], afO[8];
    f32x4 acc[4][4];
    #pragma unroll
    for (int i = 0; i < 4; ++i)
        #pragma unroll
        for (int jj = 0; jj < 4; ++jj)
            acc[i][jj] = (f32x4){0.f, 0.f, 0.f, 0.f};

    #define LOAD_A16(AF, KT)                                                 \
        _Pragma("unroll")                                                    \
        for (int q = 0; q < 8; ++q)                                          \
            AF[q] = *(const bf16x8*)(xAw + (size_t)(KT) * XT16_B + q * 1024);

    #define LOAD_B16(KT)                                                     \
        _Pragma("unroll")                                                    \
        for (int k = 0; k < 8; ++k)                                          \
            rb[k] = *(const i32x4*)(Wp + (size_t)(KT) * BK                   \
                                       + (size_t)(k * 8) * IN_F);

    #define CONVERT_B16(DSTB)                                                \
        _Pragma("unroll")                                                    \
        for (int k = 0; k < 8; ++k) {                                        \
            const int row = srow + k * 8;                                    \
            const int off = (row * 128 + scol4 * 8) ^ ((row & 7) << 4);      \
            u32x2 bv;                                                        \
            bv.x = pack2bf16_exact((float)rb[k].x, (float)rb[k].y);          \
            bv.y = pack2bf16_exact((float)rb[k].z, (float)rb[k].w);          \
            *(u32x2*)((DSTB) + off) = bv;                                    \
        }

    #define MFMA16(AF, BUFB)                                                 \
        _Pragma("unroll")                                                    \
        for (int ks = 0; ks < 2; ++ks) {                                     \
            bf16x8 bfr[4];                                                   \
            _Pragma("unroll")                                                \
            for (int ni = 0; ni < 4; ++ni) {                                 \
                const int row = ni * 16 + (lane & 15);                       \
                const int off = (row * 128 + ks * 64 + (lane >> 4) * 16)     \
                                ^ ((row & 7) << 4);                          \
                bfr[ni] = *(const bf16x8*)((BUFB) + off);                    \
            }                                                                \
            _Pragma("unroll")                                                \
            for (int mi = 0; mi < 4; ++mi)                                   \
                _Pragma("unroll")                                            \
                for (int ni = 0; ni < 4; ++ni)                               \
                    acc[mi][ni] = __builtin_amdgcn_mfma_f32_16x16x32_bf16(   \
                        AF[mi * 2 + ks], bfr[ni], acc[mi][ni], 0, 0, 0);     \
        }

    LOAD_B16(0);
    CONVERT_B16(bufB0);
    LOAD_A16(afE, 0);
    LOAD_B16(1);
    BAR();

    for (int kt2 = 0; kt2 < NKT; kt2 += 2) {
        const bool last = (kt2 == NKT - 2);
        LOAD_A16(afO, kt2 + 1);
        CONVERT_B16(bufB1);
        if (!last) LOAD_B16(kt2 + 2);
        MFMA16(afE, bufB0);
        BAR();
        if (!last) {
            LOAD_A16(afE, kt2 + 2);
            CONVERT_B16(bufB0);
            LOAD_B16(kt2 + 3);
        }
        MFMA16(afO, bufB1);
        if (!last) BAR();
    }

    #pragma unroll
    for (int ni = 0; ni < 4; ++ni) {
        const int col = bcol + ni * 16 + (lane & 15);
        const float inv = 1.0f / scale[col];
        const float bs  = bias[col];
        #pragma unroll
        for (int mi = 0; mi < 4; ++mi) {
            const int row0 = brow + w * 64 + mi * 16 + ((lane >> 4) << 2);
            #pragma unroll
            for (int jj = 0; jj < 4; ++jj)
                Out[(size_t)(row0 + jj) * OUT_F + col] = acc[mi][ni][jj] * inv + bs;
        }
    }
    #undef LOAD_A16
    #undef LOAD_B16
    #undef CONVERT_B16
    #undef MFMA16
}

// ============================ FALLBACK (no ws) ==============================

__global__ __launch_bounds__(128, 2)
void qgemm_fallback_kernel(const float* __restrict__ X,
                           const int*   __restrict__ W,
                           const float* __restrict__ scale,
                           const float* __restrict__ bias,
                           float* __restrict__ Out)
{
    __shared__ __align__(16) char smem[BM * BK * 2 + BT16_B];
    char* bufA = smem;
    char* bufB = smem + BM * BK * 2;

    const int tid  = (int)threadIdx.x;
    const int lane = tid & 63;
    const int w    = tid >> 6;

    const int bid  = (int)blockIdx.x;
    const int lbid = (bid & 7) * 86 + (bid >> 3);
    const int mtile = lbid & 3;
    const int ntile = lbid >> 2;
    const int brow = mtile * BM;
    const int bcol = ntile * BN;

    const int srow  = tid >> 4;
    const int scol4 = tid & 15;
    const int* Wp = W + (size_t)(bcol + srow) * IN_F + scol4 * 4;
    const float* Xp = X + (size_t)(brow + srow) * IN_F + scol4 * 4;

    f32x4 acc[4][4];
    #pragma unroll
    for (int i = 0; i < 4; ++i)
        #pragma unroll
        for (int jj = 0; jj < 4; ++jj)
            acc[i][jj] = (f32x4){0.f, 0.f, 0.f, 0.f};

    for (int kt = 0; kt < NKT; ++kt) {
        #pragma unroll
        for (int k = 0; k < 8; ++k) {
            i32x4 rb = *(const i32x4*)(Wp + (size_t)kt * BK + (size_t)(k * 8) * IN_F);
            const int row = srow + k * 8;
            const int off = (row * 128 + scol4 * 8) ^ ((row & 7) << 4);
            u32x2 bv;
            bv.x = pack2bf16_exact((float)rb.x, (float)rb.y);
            bv.y = pack2bf16_exact((float)rb.z, (float)rb.w);
            *(u32x2*)(bufB + off) = bv;
        }
        #pragma unroll
        for (int k = 0; k < 16; ++k) {
            f32x4 ra = *(const f32x4*)(Xp + (size_t)kt * BK + (size_t)(k * 8) * IN_F);
            const int row = srow + k * 8;
            const int off = (row * 128 + scol4 * 8) ^ ((row & 7) << 4);
            u32x2 av;
            av.x = pack2bf16_rnd(ra.x, ra.y);
            av.y = pack2bf16_rnd(ra.z, ra.w);
            *(u32x2*)(bufA + off) = av;
        }
        __syncthreads();
        #pragma unroll
        for (int ks = 0; ks < 2; ++ks) {
            bf16x8 af[4], bfr[4];
            #pragma unroll
            for (int mi = 0; mi < 4; ++mi) {
                const int row = w * 64 + mi * 16 + (lane & 15);
                const int off = (row * 128 + ks * 64 + (lane >> 4) * 16)
                                ^ ((row & 7) << 4);
                af[mi] = *(const bf16x8*)(bufA + off);
            }
            #pragma unroll
            for (int ni = 0; ni < 4; ++ni) {
                const int row = ni * 16 + (lane & 15);
                const int off = (row * 128 + ks * 64 + (lane >> 4) * 16)
                                ^ ((row & 7) << 4);
                bfr[ni] = *(const bf16x8*)(bufB + off);
            }
            #pragma unroll
            for (int mi = 0; mi < 4; ++mi)
                #pragma unroll
                for (int ni = 0; ni < 4; ++ni)
                    acc[mi][ni] = __builtin_amdgcn_mfma_f32_16x16x32_bf16(
                        af[mi], bfr[ni], acc[mi][ni], 0, 0, 0);
        }
        __syncthreads();
    }

    #pragma unroll
    for (int ni = 0; ni < 4; ++ni) {
        const int col = bcol + ni * 16 + (lane & 15);
        const float inv = 1.0f / scale[col];
        const float bs  = bias[col];
        #pragma unroll
        for (int mi = 0; mi < 4; ++mi) {
            const int row0 = brow + w * 64 + mi * 16 + ((lane >> 4) << 2);
            #pragma unroll
            for (int jj = 0; jj < 4; ++jj)
                Out[(size_t)(row0 + jj) * OUT_F + col] = acc[mi][ni][jj] * inv + bs;
        }
    }
}

extern "C" void kernel_launch(void* const* d_in, const int* in_sizes, int n_in,
                              void* d_out, int out_size, void* d_ws, size_t ws_size,
                              hipStream_t stream) {
    const float* X     = (const float*)d_in[0];
    const int*   W     = (const int*)d_in[1];
    const float* scale = (const float*)d_in[2];
    const float* bias  = (const float*)d_in[3];
    float* Out = (float*)d_out;

    const int grid = (MTOT / BM) * (OUT_F / BN);  // 688 = 8*86

    if (ws_size >= WS_FULL) {
        char*  xi8 = (char*)d_ws;
        float* sx  = (float*)((char*)d_ws + SX_OFF);
        char*  wi8 = (char*)d_ws + WWS_OFF;
        xconv_i8_kernel<<<MTOT, 256, 0, stream>>>(X, xi8, sx);
        wconv_kernel<<<OUT_F, 256, 0, stream>>>(W, wi8);
        qgemm_ff_kernel<<<grid, 128, 0, stream>>>(xi8, sx, wi8, scale, bias, Out);
    } else if (ws_size >= WS_MID) {
        char* xws = (char*)d_ws;
        xconv_bf16_kernel<<<(MTOT * IN_F / 8) / 256, 256, 0, stream>>>(X, xws);
        qgemm_bf16_kernel<<<grid, 128, 0, stream>>>(xws, W, scale, bias, Out);
    } else {
        qgemm_fallback_kernel<<<grid, 128, 0, stream>>>(X, W, scale, bias, Out);
    }
}

// Round 14
// 77.860 us; speedup vs baseline: 1.6827x; 1.6827x over previous
//
#include <hip/hip_runtime.h>
#include <hip/hip_bf16.h>
#include <stdint.h>

#define IN_F  4096
#define OUT_F 11008
#define MTOT  512

#define BM 128
#define BN 64
#define BK 64
#define NKT (IN_F / BK)            // 64 K-tiles
#define B_TILE_B (BN * BK * 2)     // 8192 B
#define XT_B 16384                 // per [mtile][kt] fragment block: 16 frags x 1 KB
#define X_WS_BYTES ((size_t)MTOT * IN_F * 2)   // 4 MiB

typedef __attribute__((ext_vector_type(4))) float  f32x4;
typedef __attribute__((ext_vector_type(4))) int    i32x4;
typedef __attribute__((ext_vector_type(2))) unsigned u32x2;
typedef __attribute__((ext_vector_type(4))) unsigned u32x4;
typedef __attribute__((ext_vector_type(8))) __bf16 bf16x8;

// f32 -> bf16 pair, round-to-nearest (for X)
__device__ __forceinline__ unsigned pack2bf16_rnd(float lo, float hi) {
    unsigned ulo = __builtin_bit_cast(unsigned, lo) + 0x8000u;
    unsigned uhi = __builtin_bit_cast(unsigned, hi) + 0x8000u;
    return __builtin_amdgcn_perm(uhi, ulo, 0x07060302u);
}
// f32 -> bf16 pair, truncation (exact for ints |q|<=127)
__device__ __forceinline__ unsigned pack2bf16_exact(float lo, float hi) {
    return __builtin_amdgcn_perm(__builtin_bit_cast(unsigned, hi),
                                 __builtin_bit_cast(unsigned, lo), 0x07060302u);
}

// LDS-only barrier: B ds_writes/ds_reads are the only cross-wave state.
// Global loads (A-frags, raw B) stay in flight across it by design.
#define BAR() do {                                                 \
    asm volatile("s_waitcnt lgkmcnt(0)" ::: "memory");             \
    __builtin_amdgcn_s_barrier();                                  \
    __builtin_amdgcn_sched_barrier(0);                             \
} while (0)

// ---- Prepass: X fp32 -> bf16 in MFMA-FRAGMENT order (R8-verified) ----
// xws layout: [mtile][kt][f = mi*2+ks][lane][16B], 16 KB per (mtile,kt).
__global__ __launch_bounds__(256)
void xconv_kernel(const float* __restrict__ X, char* __restrict__ xws) {
    const int gid  = blockIdx.x * 256 + threadIdx.x;   // 262144 threads
    const int row  = gid >> 9;
    const int col0 = (gid & 511) * 8;
    const float* src = X + (size_t)row * IN_F + col0;
    f32x4 v0 = *(const f32x4*)(src);
    f32x4 v1 = *(const f32x4*)(src + 4);
    u32x4 o;
    o.x = pack2bf16_rnd(v0.x, v0.y);
    o.y = pack2bf16_rnd(v0.z, v0.w);
    o.z = pack2bf16_rnd(v1.x, v1.y);
    o.w = pack2bf16_rnd(v1.z, v1.w);
    const int mtile = row >> 7, mrow = row & 127;
    const int mi = mrow >> 4,  l15 = mrow & 15;
    const int kt  = col0 >> 6;
    const int ks  = (col0 >> 5) & 1;
    const int lhi = (col0 >> 3) & 3;
    const int lane = lhi * 16 + l15;
    const int f = mi * 2 + ks;
    *(u32x4*)(xws + ((size_t)(mtile * NKT + kt) * 16 + f) * 1024
                  + lane * 16) = o;
}

// ---- Main GEMM: R8 structure with 4 waves x (32x64) wave tiles.
//      Byte-identical to R8 (same A frag-direct, same B raw->LDS dbuf, same
//      swizzle, same lgkm-only barrier); only the wave decomposition changes:
//      waves/CU 5.4 -> 10.75 for latency overlap. ----
__global__ __launch_bounds__(256, 3)
void qgemm_kernel(const char* __restrict__ xws,
                  const int*   __restrict__ W,
                  const float* __restrict__ scale,
                  const float* __restrict__ bias,
                  float* __restrict__ Out)
{
    __shared__ __align__(16) char smem[2 * B_TILE_B];  // 16 KiB
    char* bufB0 = smem;
    char* bufB1 = smem + B_TILE_B;

    const int tid  = (int)threadIdx.x;
    const int lane = tid & 63;
    const int w    = tid >> 6;     // 0..3 -> rows [w*32, w*32+32)

    // XCD mapping (R2/R5/R8-proven): 688 = 8*86 exact; the 4 mtiles of one
    // ntile are consecutive within an XCD -> W panel L2-shared 4-way.
    const int bid  = (int)blockIdx.x;
    const int lbid = (bid & 7) * 86 + (bid >> 3);
    const int mtile = lbid & 3;
    const int ntile = lbid >> 2;
    const int brow = mtile * BM;
    const int bcol = ntile * BN;

    // B staging: thread t covers rows (t>>4) + k*16 (k=0..3), chunk t&15.
    const int srow  = tid >> 4;    // 0..15
    const int scol4 = tid & 15;    // 0..15
    const int* Wp = W + (size_t)(bcol + srow) * IN_F + scol4 * 4;

    // Wave w owns A frags f = w*4 + q (q=0..3): rows w*32 + (q>>1)*16 + l15,
    // K-half q&1. Base offset w*4096.
    const char* xAw = xws + (size_t)mtile * (NKT * XT_B) + w * 4096 + lane * 16;

    i32x4 rb[4];
    bf16x8 afE[4], afO[4];
    f32x4 acc[2][4];
    #pragma unroll
    for (int i = 0; i < 2; ++i)
        #pragma unroll
        for (int jj = 0; jj < 4; ++jj)
            acc[i][jj] = (f32x4){0.f, 0.f, 0.f, 0.f};

    #define LOAD_A(AF, KT)                                                   \
        _Pragma("unroll")                                                    \
        for (int q = 0; q < 4; ++q)                                          \
            AF[q] = *(const bf16x8*)(xAw + (size_t)(KT) * XT_B + q * 1024);

    #define LOAD_B(KT)                                                       \
        _Pragma("unroll")                                                    \
        for (int k = 0; k < 4; ++k)                                          \
            rb[k] = *(const i32x4*)(Wp + (size_t)(KT) * BK                   \
                                       + (size_t)(k * 16) * IN_F);

    #define CONVERT_B(DSTB)                                                  \
        _Pragma("unroll")                                                    \
        for (int k = 0; k < 4; ++k) {                                        \
            const int row = srow + k * 16;                                   \
            const int off = (row * 128 + scol4 * 8) ^ ((row & 7) << 4);      \
            u32x2 bv;                                                        \
            bv.x = pack2bf16_exact((float)rb[k].x, (float)rb[k].y);          \
            bv.y = pack2bf16_exact((float)rb[k].z, (float)rb[k].w);          \
            *(u32x2*)((DSTB) + off) = bv;                                    \
        }

    #define MFMA_PHASE(AF, BUFB)                                             \
        _Pragma("unroll")                                                    \
        for (int ks = 0; ks < 2; ++ks) {                                     \
            bf16x8 bfr[4];                                                   \
            _Pragma("unroll")                                                \
            for (int ni = 0; ni < 4; ++ni) {                                 \
                const int row = ni * 16 + (lane & 15);                       \
                const int off = (row * 128 + ks * 64 + (lane >> 4) * 16)     \
                                ^ ((row & 7) << 4);                          \
                bfr[ni] = *(const bf16x8*)((BUFB) + off);                    \
            }                                                                \
            _Pragma("unroll")                                                \
            for (int mi = 0; mi < 2; ++mi)                                   \
                _Pragma("unroll")                                            \
                for (int ni = 0; ni < 4; ++ni)                               \
                    acc[mi][ni] = __builtin_amdgcn_mfma_f32_16x16x32_bf16(   \
                        AF[mi * 2 + ks], bfr[ni], acc[mi][ni], 0, 0, 0);     \
        }

    // ---------- prologue (R8 structure) ----------
    LOAD_B(0);
    CONVERT_B(bufB0);          // compiler waits the rb loads
    LOAD_A(afE, 0);
    LOAD_B(1);
    BAR();                     // publish bufB0

    // ---------- main loop: pairs (even kt2, odd kt2+1), R8 structure ----------
    for (int kt2 = 0; kt2 < NKT; kt2 += 2) {
        const bool last = (kt2 == NKT - 2);

        // ===== even kt = kt2: compute bufB0/afE, fill bufB1 =====
        LOAD_A(afO, kt2 + 1);
        CONVERT_B(bufB1);             // B(kt2+1) from rb
        if (!last) LOAD_B(kt2 + 2);
        MFMA_PHASE(afE, bufB0);
        BAR();                        // publish bufB1

        // ===== odd kt = kt2+1: compute bufB1/afO, fill bufB0 =====
        if (!last) {
            LOAD_A(afE, kt2 + 2);
            CONVERT_B(bufB0);         // B(kt2+2) from rb
            LOAD_B(kt2 + 3);
        }
        MFMA_PHASE(afO, bufB1);
        if (!last) BAR();             // publish bufB0
    }

    // --- epilogue: out = acc / scale[col] + bias[col] ---
    // C/D mapping: col = lane&15, row = (lane>>4)*4 + j
    #pragma unroll
    for (int ni = 0; ni < 4; ++ni) {
        const int col = bcol + ni * 16 + (lane & 15);
        const float inv = 1.0f / scale[col];
        const float bs  = bias[col];
        #pragma unroll
        for (int mi = 0; mi < 2; ++mi) {
            const int row0 = brow + w * 32 + mi * 16 + ((lane >> 4) << 2);
            #pragma unroll
            for (int jj = 0; jj < 4; ++jj)
                Out[(size_t)(row0 + jj) * OUT_F + col] = acc[mi][ni][jj] * inv + bs;
        }
    }

    #undef LOAD_A
    #undef LOAD_B
    #undef CONVERT_B
    #undef MFMA_PHASE
}

// ---- Fallback (ws too small): full-K kernel, LDS-staged both operands ----
__global__ __launch_bounds__(128, 2)
void qgemm_fallback_kernel(const float* __restrict__ X,
                           const int*   __restrict__ W,
                           const float* __restrict__ scale,
                           const float* __restrict__ bias,
                           float* __restrict__ Out)
{
    __shared__ __align__(16) char smem[BM * BK * 2 + B_TILE_B];
    char* bufA = smem;
    char* bufB = smem + BM * BK * 2;

    const int tid  = (int)threadIdx.x;
    const int lane = tid & 63;
    const int w    = tid >> 6;

    const int bid  = (int)blockIdx.x;
    const int lbid = (bid & 7) * 86 + (bid >> 3);
    const int mtile = lbid & 3;
    const int ntile = lbid >> 2;
    const int brow = mtile * BM;
    const int bcol = ntile * BN;

    const int srow  = tid >> 4;
    const int scol4 = tid & 15;
    const int* Wp = W + (size_t)(bcol + srow) * IN_F + scol4 * 4;
    const float* Xp = X + (size_t)(brow + srow) * IN_F + scol4 * 4;

    f32x4 acc[4][4];
    #pragma unroll
    for (int i = 0; i < 4; ++i)
        #pragma unroll
        for (int jj = 0; jj < 4; ++jj)
            acc[i][jj] = (f32x4){0.f, 0.f, 0.f, 0.f};

    for (int kt = 0; kt < NKT; ++kt) {
        #pragma unroll
        for (int k = 0; k < 8; ++k) {
            i32x4 rb = *(const i32x4*)(Wp + (size_t)kt * BK + (size_t)(k * 8) * IN_F);
            const int row = srow + k * 8;
            const int off = (row * 128 + scol4 * 8) ^ ((row & 7) << 4);
            u32x2 bv;
            bv.x = pack2bf16_exact((float)rb.x, (float)rb.y);
            bv.y = pack2bf16_exact((float)rb.z, (float)rb.w);
            *(u32x2*)(bufB + off) = bv;
        }
        #pragma unroll
        for (int k = 0; k < 16; ++k) {
            f32x4 ra = *(const f32x4*)(Xp + (size_t)kt * BK + (size_t)(k * 8) * IN_F);
            const int row = srow + k * 8;
            const int off = (row * 128 + scol4 * 8) ^ ((row & 7) << 4);
            u32x2 av;
            av.x = pack2bf16_rnd(ra.x, ra.y);
            av.y = pack2bf16_rnd(ra.z, ra.w);
            *(u32x2*)(bufA + off) = av;
        }
        __syncthreads();
        #pragma unroll
        for (int ks = 0; ks < 2; ++ks) {
            bf16x8 af[4], bfr[4];
            #pragma unroll
            for (int mi = 0; mi < 4; ++mi) {
                const int row = w * 64 + mi * 16 + (lane & 15);
                const int off = (row * 128 + ks * 64 + (lane >> 4) * 16)
                                ^ ((row & 7) << 4);
                af[mi] = *(const bf16x8*)(bufA + off);
            }
            #pragma unroll
            for (int ni = 0; ni < 4; ++ni) {
                const int row = ni * 16 + (lane & 15);
                const int off = (row * 128 + ks * 64 + (lane >> 4) * 16)
                                ^ ((row & 7) << 4);
                bfr[ni] = *(const bf16x8*)(bufB + off);
            }
            #pragma unroll
            for (int mi = 0; mi < 4; ++mi)
                #pragma unroll
                for (int ni = 0; ni < 4; ++ni)
                    acc[mi][ni] = __builtin_amdgcn_mfma_f32_16x16x32_bf16(
                        af[mi], bfr[ni], acc[mi][ni], 0, 0, 0);
        }
        __syncthreads();
    }

    #pragma unroll
    for (int ni = 0; ni < 4; ++ni) {
        const int col = bcol + ni * 16 + (lane & 15);
        const float inv = 1.0f / scale[col];
        const float bs  = bias[col];
        #pragma unroll
        for (int mi = 0; mi < 4; ++mi) {
            const int row0 = brow + w * 64 + mi * 16 + ((lane >> 4) << 2);
            #pragma unroll
            for (int jj = 0; jj < 4; ++jj)
                Out[(size_t)(row0 + jj) * OUT_F + col] = acc[mi][ni][jj] * inv + bs;
        }
    }
}

extern "C" void kernel_launch(void* const* d_in, const int* in_sizes, int n_in,
                              void* d_out, int out_size, void* d_ws, size_t ws_size,
                              hipStream_t stream) {
    const float* X     = (const float*)d_in[0];
    const int*   W     = (const int*)d_in[1];
    const float* scale = (const float*)d_in[2];
    const float* bias  = (const float*)d_in[3];
    float* Out = (float*)d_out;

    const int grid = (MTOT / BM) * (OUT_F / BN);  // 688 = 8*86

    if (ws_size >= X_WS_BYTES) {
        char* xws = (char*)d_ws;
        xconv_kernel<<<(MTOT * IN_F / 8) / 256, 256, 0, stream>>>(X, xws);
        qgemm_kernel<<<grid, 256, 0, stream>>>(xws, W, scale, bias, Out);
    } else {
        qgemm_fallback_kernel<<<grid, 128, 0, stream>>>(X, W, scale, bias, Out);
    }
}